// Round 3
// baseline (2439.464 us; speedup 1.0000x reference)
//
#include <hip/hip_runtime.h>
#include <cstdint>
#include <cstddef>

// ---------- helpers ----------
__device__ __forceinline__ unsigned short f2h(float f) {
    union { _Float16 h; unsigned short u; } c; c.h = (_Float16)f; return c.u;
}
__device__ __forceinline__ float h2f(unsigned short u) {
    union { unsigned short u; _Float16 h; } c; c.u = u; return (float)c.h;
}

typedef _Float16 f16x8 __attribute__((ext_vector_type(8)));
typedef float    f32x4 __attribute__((ext_vector_type(4)));

// async global->LDS, 16B per lane. HW: LDS dest = wave-uniform base + lane*16.
__device__ __forceinline__ void gload16(const void* g, void* l) {
    __builtin_amdgcn_global_load_lds(
        (const __attribute__((address_space(1))) unsigned int*)g,
        (__attribute__((address_space(3))) unsigned int*)l,
        16, 0, 0);
}

// ---------- f32 -> f16 elementwise (input_tensor), 8 elems/thread ----------
__global__ __launch_bounds__(256) void cvt_f32_f16(const float* __restrict__ in,
                                                   _Float16* __restrict__ out) {
    const size_t i = ((size_t)blockIdx.x * 256 + threadIdx.x) * 8;
    const float4 a = *(const float4*)(in + i);
    const float4 b = *(const float4*)(in + i + 4);
    f16x8 v;
    v[0] = (_Float16)a.x; v[1] = (_Float16)a.y; v[2] = (_Float16)a.z; v[3] = (_Float16)a.w;
    v[4] = (_Float16)b.x; v[5] = (_Float16)b.y; v[6] = (_Float16)b.z; v[7] = (_Float16)b.w;
    *(f16x8*)(out + i) = v;
}

// ---------- transpose + f32->f16: in[R][C] (f32) -> out[C][R] (f16) ----------
// 64x64 tiles, 256 threads. R, C multiples of 64.
__global__ __launch_bounds__(256) void transpose_cvt64(const float* __restrict__ in,
                                                       _Float16* __restrict__ out,
                                                       int R, int C) {
    __shared__ __align__(16) _Float16 tile[64][68];   // transposed store; rows 8B-aligned
    const int t = threadIdx.x;
    const int r0 = blockIdx.y << 6, c0 = blockIdx.x << 6;
#pragma unroll
    for (int p = 0; p < 4; ++p) {
        const int id  = p * 256 + t;          // 0..1023
        const int row = id >> 4;              // 0..63
        const int cg  = (id & 15) << 2;       // 0..60
        const float4 v = *(const float4*)(in + (size_t)(r0 + row) * C + (c0 + cg));
        tile[cg + 0][row] = (_Float16)v.x;
        tile[cg + 1][row] = (_Float16)v.y;
        tile[cg + 2][row] = (_Float16)v.z;
        tile[cg + 3][row] = (_Float16)v.w;
    }
    __syncthreads();
#pragma unroll
    for (int p = 0; p < 4; ++p) {
        const int id   = p * 256 + t;
        const int crow = id >> 4;             // output row (input col)
        const int rg   = (id & 15) << 2;
        ushort4 v;
        v.x = ((const unsigned short*)&tile[crow][rg])[0];
        v.y = ((const unsigned short*)&tile[crow][rg])[1];
        v.z = ((const unsigned short*)&tile[crow][rg])[2];
        v.w = ((const unsigned short*)&tile[crow][rg])[3];
        *(ushort4*)((unsigned short*)out + (size_t)(c0 + crow) * R + (r0 + rg)) = v;
    }
}

// ---------- GEMM: C = A[MxK] * BT[NxK]^T, m97 structure ----------
// EPI 0: o16 = f16(acc + bias)                        (shared input proj -> h)
// EPI 1: o16 = f16(relu(acc + bias))                  (expert layer 1 -> e1)
// EPI 2: o16 (+)= f16(ew[m,e] * relu(acc + bias))     (expert layer 2 -> combined, RMW)
// EPI 3: of32 = acc + bias                            (output proj -> preLN)
template <int EPI>
__global__ __launch_bounds__(256) void gemm_bt(
    const _Float16* __restrict__ A,          // M x K (f16)
    const _Float16* __restrict__ BT,         // N x K (f16)
    const float* __restrict__ bias,          // f32 [N]
    unsigned short* __restrict__ o16,        // f16 out
    float* __restrict__ of32,                // f32 out
    const float* __restrict__ ew,            // f32 [M][8]
    int M, int N, int K, int expert, int first)
{
    __shared__ __align__(16) _Float16 As[128 * 32];
    __shared__ __align__(16) _Float16 Bs[128 * 32];

    const int tid  = threadIdx.x;
    const int lane = tid & 63, wave = tid >> 6;
    const int quad = lane >> 4, r16 = lane & 15;
    const int wr = wave >> 1, wc = wave & 1;
    const int m0 = blockIdx.y << 7, n0 = blockIdx.x << 7;

    f32x4 acc[4][4];
#pragma unroll
    for (int i = 0; i < 4; ++i)
#pragma unroll
        for (int j = 0; j < 4; ++j)
#pragma unroll
            for (int r = 0; r < 4; ++r) acc[i][j][r] = 0.f;

    // staging: chunk c = r*256+tid -> LDS byte c*16; global row r*64+tid/4, k-col (tid&3)*8
    const int srow = tid >> 2;
    const int scol = (tid & 3) << 3;
    const _Float16* ga  = A  + (size_t)(m0 + srow) * K + scol;
    const _Float16* ga2 = ga + (size_t)64 * K;
    const _Float16* gb  = BT + (size_t)(n0 + srow) * K + scol;
    const _Float16* gb2 = gb + (size_t)64 * K;
    _Float16* la  = As + tid * 8;
    _Float16* la2 = As + 2048 + tid * 8;
    _Float16* lb  = Bs + tid * 8;
    _Float16* lb2 = Bs + 2048 + tid * 8;

    for (int kt = 0; kt < K; kt += 32) {
        gload16(ga + kt, la);  gload16(ga2 + kt, la2);
        gload16(gb + kt, lb);  gload16(gb2 + kt, lb2);
        __syncthreads();       // compiler emits s_waitcnt vmcnt(0) before s_barrier

        f16x8 af[4], bf[4];
#pragma unroll
        for (int i = 0; i < 4; ++i)
            af[i] = *(const f16x8*)(As + (wr * 64 + i * 16 + r16) * 32 + quad * 8);
#pragma unroll
        for (int j = 0; j < 4; ++j)
            bf[j] = *(const f16x8*)(Bs + (wc * 64 + j * 16 + r16) * 32 + quad * 8);

#pragma unroll
        for (int i = 0; i < 4; ++i)
#pragma unroll
            for (int j = 0; j < 4; ++j)
                acc[i][j] = __builtin_amdgcn_mfma_f32_16x16x32_f16(af[i], bf[j], acc[i][j], 0, 0, 0);
        __syncthreads();       // protect LDS from next iteration's staging
    }

    // epilogue: C row m = m0+wr*64+i*16+quad*4+r, col n = n0+wc*64+j*16+r16
    float bj[4];
#pragma unroll
    for (int j = 0; j < 4; ++j) bj[j] = bias[n0 + wc * 64 + j * 16 + r16];

#pragma unroll
    for (int i = 0; i < 4; ++i) {
        const int mb = m0 + wr * 64 + i * 16 + quad * 4;
#pragma unroll
        for (int r = 0; r < 4; ++r) {
            const int m = mb + r;
            float w = 0.f;
            if (EPI == 2) w = ew[(size_t)m * 8 + expert];
#pragma unroll
            for (int j = 0; j < 4; ++j) {
                const int n = n0 + wc * 64 + j * 16 + r16;
                const size_t idx = (size_t)m * N + n;
                float v = acc[i][j][r] + bj[j];
                if (EPI == 0) {
                    o16[idx] = f2h(v);
                } else if (EPI == 1) {
                    o16[idx] = f2h(fmaxf(v, 0.f));
                } else if (EPI == 2) {
                    float t = w * fmaxf(v, 0.f);
                    if (!first) t += h2f(o16[idx]);
                    o16[idx] = f2h(t);
                } else {
                    of32[idx] = v;
                }
            }
        }
    }
}

// ---------- LayerNorm over D=1024, fp32 in -> fp32 out ----------
__global__ __launch_bounds__(256) void ln_rows(const float* __restrict__ x,
                                               const float* __restrict__ gamma,
                                               const float* __restrict__ beta,
                                               float* __restrict__ out) {
    const int row = blockIdx.x;
    const int t = threadIdx.x;
    const float4 v = *(const float4*)(x + (size_t)row * 1024 + t * 4);
    float s  = v.x + v.y + v.z + v.w;
    float ss = v.x * v.x + v.y * v.y + v.z * v.z + v.w * v.w;
#pragma unroll
    for (int off = 32; off > 0; off >>= 1) {
        s  += __shfl_down(s,  off, 64);
        ss += __shfl_down(ss, off, 64);
    }
    __shared__ float red[8];
    const int lane = t & 63, wv = t >> 6;
    if (lane == 0) { red[wv] = s; red[4 + wv] = ss; }
    __syncthreads();
    const float S  = red[0] + red[1] + red[2] + red[3];
    const float SS = red[4] + red[5] + red[6] + red[7];
    const float mean = S * (1.f / 1024.f);
    const float var  = SS * (1.f / 1024.f) - mean * mean;
    const float rstd = rsqrtf(var + 1e-5f);
    const float4 g4 = *(const float4*)(gamma + t * 4);
    const float4 b4 = *(const float4*)(beta + t * 4);
    float4 o;
    o.x = (v.x - mean) * rstd * g4.x + b4.x;
    o.y = (v.y - mean) * rstd * g4.y + b4.y;
    o.z = (v.z - mean) * rstd * g4.z + b4.z;
    o.w = (v.w - mean) * rstd * g4.w + b4.w;
    *(float4*)(out + (size_t)row * 1024 + t * 4) = o;
}

// ---------- host ----------
extern "C" void kernel_launch(void* const* d_in, const int* in_sizes, int n_in,
                              void* d_out, int out_size, void* d_ws, size_t ws_size,
                              hipStream_t stream) {
    const int M = 8192, D = 1024, H = 2048, E = 8;

    const float* X  = (const float*)d_in[0];    // [M][D]
    const float* EW = (const float*)d_in[1];    // [M][E]
    const float* Wi = (const float*)d_in[2];    // [D][H]
    const float* bi = (const float*)d_in[3];    // [H]
    const float* W1 = (const float*)d_in[4];    // [E][H][H]
    const float* b1 = (const float*)d_in[5];    // [E][H]
    const float* W2 = (const float*)d_in[6];    // [E][H][H]
    const float* b2 = (const float*)d_in[7];    // [E][H]
    const float* Wo = (const float*)d_in[8];    // [H][D]
    const float* bo = (const float*)d_in[9];    // [D]
    const float* gm = (const float*)d_in[10];   // [D]
    const float* bt = (const float*)d_in[11];   // [D]

    char* wsp = (char*)d_ws;
    size_t off = 0;
    auto alloc = [&](size_t bytes) { char* p = wsp + off; off += bytes; return p; };
    _Float16* WiT  = (_Float16*)alloc((size_t)H * D * 2);        //  4 MB  [H][D]
    _Float16* WoT  = (_Float16*)alloc((size_t)D * H * 2);        //  4 MB  [D][H]
    _Float16* W1Te = (_Float16*)alloc((size_t)H * H * 2);        //  8 MB
    _Float16* W2Te = (_Float16*)alloc((size_t)H * H * 2);        //  8 MB
    _Float16* Xh   = (_Float16*)alloc((size_t)M * D * 2);        // 16 MB
    _Float16* h    = (_Float16*)alloc((size_t)M * H * 2);        // 32 MB
    _Float16* e1   = (_Float16*)alloc((size_t)M * H * 2);        // 32 MB
    _Float16* cmb  = (_Float16*)alloc((size_t)M * H * 2);        // 32 MB  combined (f16, RMW)
    float* preLN   = (float*)h;                                  // alias: h dead after last GEMM2

    dim3 blk(256);

    cvt_f32_f16<<<(M * D) / 2048, blk, 0, stream>>>(X, Xh);
    transpose_cvt64<<<dim3(H / 64, D / 64), blk, 0, stream>>>(Wi, WiT, D, H);
    transpose_cvt64<<<dim3(D / 64, H / 64), blk, 0, stream>>>(Wo, WoT, H, D);

    // GEMM1: h = X*Wi + bi
    gemm_bt<0><<<dim3(H / 128, M / 128), blk, 0, stream>>>(
        Xh, WiT, bi, (unsigned short*)h, nullptr, nullptr, M, H, D, 0, 0);

    for (int e = 0; e < E; ++e) {
        transpose_cvt64<<<dim3(H / 64, H / 64), blk, 0, stream>>>(
            W1 + (size_t)e * H * H, W1Te, H, H);
        gemm_bt<1><<<dim3(H / 128, M / 128), blk, 0, stream>>>(
            h, W1Te, b1 + (size_t)e * H, (unsigned short*)e1, nullptr, nullptr, M, H, H, 0, 0);
        transpose_cvt64<<<dim3(H / 64, H / 64), blk, 0, stream>>>(
            W2 + (size_t)e * H * H, W2Te, H, H);
        gemm_bt<2><<<dim3(H / 128, M / 128), blk, 0, stream>>>(
            e1, W2Te, b2 + (size_t)e * H, (unsigned short*)cmb, nullptr, EW, M, H, H, e, e == 0);
    }

    // GEMM4: preLN = combined*Wo + bo  (fp32 out)
    gemm_bt<3><<<dim3(D / 128, M / 128), blk, 0, stream>>>(
        cmb, WoT, bo, nullptr, preLN, nullptr, M, D, H, 0, 0);

    ln_rows<<<M, blk, 0, stream>>>(preLN, gm, bt, (float*)d_out);
}